// Round 4
// baseline (586.037 us; speedup 1.0000x reference)
//
#include <hip/hip_runtime.h>
#include <math.h>

#define CAP 96   // max in-degree bucket capacity; deg ~ Poisson(16), P(deg>=96) ~ 1e-30

// ---------------- CSR-bucket build ----------------

__global__ void fill_k(const int* __restrict__ src, const int* __restrict__ dst,
                       int E, int* __restrict__ cnt, int* __restrict__ bkt) {
    int e = blockIdx.x * blockDim.x + threadIdx.x;
    if (e < E) {
        int d = dst[e];
        int pos = atomicAdd(&cnt[d], 1);
        if (pos < CAP) bkt[(size_t)d * CAP + pos] = src[e];
    }
}

__global__ void dinv_k(const int* __restrict__ cnt, float* __restrict__ dinv, int n) {
    int v = blockIdx.x * blockDim.x + threadIdx.x;
    if (v < n) dinv[v] = rsqrtf((float)(cnt[v] + 1));  // +1 self-loop
}

// ---------------- gather hop: one wave per node, float2 per lane ----------------
// SCALE_SRC=true  (hop1): out[v] = dinv[v]^2 * ( sum_e x[src]*dinv[src] + x[v]*dinv[v] )
// SCALE_SRC=false (hop2): out[v] = dinv[v]   * ( sum_e z[src]           + z[v]          )

template<bool SCALE_SRC>
__global__ __launch_bounds__(256) void gather_hop_k(
    const float2* __restrict__ xin,
    const int* __restrict__ cnt, const int* __restrict__ bkt,
    const float* __restrict__ dinv,
    float2* __restrict__ xout, int n)
{
    int v = blockIdx.x * (blockDim.x >> 6) + (threadIdx.x >> 6);
    if (v >= n) return;
    int l = threadIdx.x & 63;
    int c = cnt[v]; if (c > CAP) c = CAP;
    const int* __restrict__ b = bkt + (size_t)v * CAP;

    float2 acc = make_float2(0.f, 0.f);
    int i = 0;
    for (; i + 4 <= c; i += 4) {           // 4-edge unroll: memory-level parallelism
        int s0 = b[i], s1 = b[i + 1], s2 = b[i + 2], s3 = b[i + 3];
        float2 v0 = xin[(size_t)s0 * 64 + l];
        float2 v1 = xin[(size_t)s1 * 64 + l];
        float2 v2 = xin[(size_t)s2 * 64 + l];
        float2 v3 = xin[(size_t)s3 * 64 + l];
        if (SCALE_SRC) {
            float d0 = dinv[s0], d1 = dinv[s1], d2 = dinv[s2], d3 = dinv[s3];
            acc.x = fmaf(v0.x, d0, acc.x); acc.y = fmaf(v0.y, d0, acc.y);
            acc.x = fmaf(v1.x, d1, acc.x); acc.y = fmaf(v1.y, d1, acc.y);
            acc.x = fmaf(v2.x, d2, acc.x); acc.y = fmaf(v2.y, d2, acc.y);
            acc.x = fmaf(v3.x, d3, acc.x); acc.y = fmaf(v3.y, d3, acc.y);
        } else {
            acc.x += (v0.x + v1.x) + (v2.x + v3.x);
            acc.y += (v0.y + v1.y) + (v2.y + v3.y);
        }
    }
    for (; i < c; i++) {
        int s0 = b[i];
        float2 v0 = xin[(size_t)s0 * 64 + l];
        if (SCALE_SRC) {
            float d0 = dinv[s0];
            acc.x = fmaf(v0.x, d0, acc.x); acc.y = fmaf(v0.y, d0, acc.y);
        } else {
            acc.x += v0.x; acc.y += v0.y;
        }
    }

    float dv = dinv[v];
    float2 self = xin[(size_t)v * 64 + l];
    if (SCALE_SRC) {
        acc.x = fmaf(self.x, dv, acc.x);
        acc.y = fmaf(self.y, dv, acc.y);
        float s2 = dv * dv;
        acc.x *= s2; acc.y *= s2;
    } else {
        acc.x = (acc.x + self.x) * dv;
        acc.y = (acc.y + self.y) * dv;
    }
    xout[(size_t)v * 64 + l] = acc;
}

// ---------------- fused MLP + log_softmax ----------------
// 256 threads, 64 nodes per block. Register-tiled: layer1 = 8 nodes x 4 feats
// per thread; layer2 = 4 nodes x 4 logits per thread; shfl-based softmax.
__global__ __launch_bounds__(256, 4) void transform_k(
    const float4* __restrict__ x2,
    const float* __restrict__ W1, const float* __restrict__ b1,
    const float* __restrict__ W2, const float* __restrict__ b2,
    float* __restrict__ out, int n)
{
    __shared__ float xs[64][132];   // x tile, then reused for h tile (row pad: 528B, 16B-aligned)

    int t = threadIdx.x;
    int node0 = blockIdx.x * 64;

    // stage x tile: 64 rows x 32 float4
    for (int i = t; i < 64 * 32; i += 256) {
        int nn = i >> 5, j4 = i & 31;
        int node = node0 + nn;
        float4 v = make_float4(0.f, 0.f, 0.f, 0.f);
        if (node < n) v = x2[(size_t)node * 32 + j4];
        *(float4*)&xs[nn][j4 * 4] = v;
    }
    __syncthreads();

    // ---- layer 1: h[64][128] = relu(x @ W1^T + b1) ----
    int ftid = t & 31;          // 32 feature-groups of 4
    int ntid = t >> 5;          // 8 node-groups of 8
    float acc[8][4];
    {
        float4 bb = *(const float4*)&b1[ftid * 4];
#pragma unroll
        for (int i = 0; i < 8; i++) {
            acc[i][0] = bb.x; acc[i][1] = bb.y; acc[i][2] = bb.z; acc[i][3] = bb.w;
        }
    }
    for (int k4 = 0; k4 < 32; k4++) {
        float4 w[4];
#pragma unroll
        for (int j = 0; j < 4; j++)
            w[j] = *(const float4*)&W1[(size_t)(ftid * 4 + j) * 128 + k4 * 4];
#pragma unroll
        for (int i = 0; i < 8; i++) {
            float4 xv = *(const float4*)&xs[ntid * 8 + i][k4 * 4];  // wave-broadcast (2 addrs/instr)
#pragma unroll
            for (int j = 0; j < 4; j++) {
                acc[i][j] = fmaf(xv.x, w[j].x, acc[i][j]);
                acc[i][j] = fmaf(xv.y, w[j].y, acc[i][j]);
                acc[i][j] = fmaf(xv.z, w[j].z, acc[i][j]);
                acc[i][j] = fmaf(xv.w, w[j].w, acc[i][j]);
            }
        }
    }
    __syncthreads();   // all x reads done; safe to overwrite with h
#pragma unroll
    for (int i = 0; i < 8; i++) {
        float4 h4 = make_float4(fmaxf(acc[i][0], 0.f), fmaxf(acc[i][1], 0.f),
                                fmaxf(acc[i][2], 0.f), fmaxf(acc[i][3], 0.f));
        *(float4*)&xs[ntid * 8 + i][ftid * 4] = h4;
    }
    __syncthreads();

    // ---- layer 2: logits[64][64] = h @ W2^T + b2 ----
    int ltid = t & 15;          // 16 logit-groups of 4
    int ntid2 = t >> 4;         // 16 node-groups of 4
    float acc2[4][4];
    {
        float4 bb = *(const float4*)&b2[ltid * 4];
#pragma unroll
        for (int i = 0; i < 4; i++) {
            acc2[i][0] = bb.x; acc2[i][1] = bb.y; acc2[i][2] = bb.z; acc2[i][3] = bb.w;
        }
    }
    for (int k4 = 0; k4 < 32; k4++) {
        float4 w[4];
#pragma unroll
        for (int j = 0; j < 4; j++)
            w[j] = *(const float4*)&W2[(size_t)(ltid * 4 + j) * 128 + k4 * 4];
#pragma unroll
        for (int i = 0; i < 4; i++) {
            float4 hv = *(const float4*)&xs[ntid2 * 4 + i][k4 * 4];
#pragma unroll
            for (int j = 0; j < 4; j++) {
                acc2[i][j] = fmaf(hv.x, w[j].x, acc2[i][j]);
                acc2[i][j] = fmaf(hv.y, w[j].y, acc2[i][j]);
                acc2[i][j] = fmaf(hv.z, w[j].z, acc2[i][j]);
                acc2[i][j] = fmaf(hv.w, w[j].w, acc2[i][j]);
            }
        }
    }

    // ---- log_softmax per node across the 16 threads holding its 64 logits ----
#pragma unroll
    for (int i = 0; i < 4; i++) {
        float m = fmaxf(fmaxf(acc2[i][0], acc2[i][1]), fmaxf(acc2[i][2], acc2[i][3]));
        m = fmaxf(m, __shfl_xor(m, 1, 16));
        m = fmaxf(m, __shfl_xor(m, 2, 16));
        m = fmaxf(m, __shfl_xor(m, 4, 16));
        m = fmaxf(m, __shfl_xor(m, 8, 16));
        float s = __expf(acc2[i][0] - m) + __expf(acc2[i][1] - m) +
                  __expf(acc2[i][2] - m) + __expf(acc2[i][3] - m);
        s += __shfl_xor(s, 1, 16);
        s += __shfl_xor(s, 2, 16);
        s += __shfl_xor(s, 4, 16);
        s += __shfl_xor(s, 8, 16);
        float lse = m + __logf(s);
        int node = node0 + ntid2 * 4 + i;
        if (node < n) {
            float4 o = make_float4(acc2[i][0] - lse, acc2[i][1] - lse,
                                   acc2[i][2] - lse, acc2[i][3] - lse);
            *(float4*)&out[(size_t)node * 64 + ltid * 4] = o;
        }
    }
}

// ---------------- launch ----------------

static inline size_t align256(size_t x) { return (x + 255) & ~(size_t)255; }

extern "C" void kernel_launch(void* const* d_in, const int* in_sizes, int n_in,
                              void* d_out, int out_size, void* d_ws, size_t ws_size,
                              hipStream_t stream) {
    const float* x  = (const float*)d_in[0];
    const int*   ei = (const int*)d_in[1];
    const float* W1 = (const float*)d_in[2];
    const float* b1 = (const float*)d_in[3];
    const float* W2 = (const float*)d_in[4];
    const float* b2 = (const float*)d_in[5];
    float* out = (float*)d_out;

    int n = in_sizes[0] / 128;        // 100000
    int E = in_sizes[1] / 2;          // 1600000
    const int* src = ei;
    const int* dst = ei + E;

    // workspace layout
    char* w = (char*)d_ws;
    size_t off = 0;
    int*   cnt  = (int*)(w + off);   off += align256((size_t)n * sizeof(int));
    float* dinv = (float*)(w + off); off += align256((size_t)n * sizeof(float));
    int*   bkt  = (int*)(w + off);   off += align256((size_t)n * CAP * sizeof(int));
    float* z1   = (float*)(w + off); off += align256((size_t)n * 128 * sizeof(float));
    float* x2   = (float*)(w + off);

    int tb = 256;
    int gb_n = (n + tb - 1) / tb;
    int gb_E = (E + tb - 1) / tb;
    int nodes_per_blk = tb / 64;
    int gb_g = (n + nodes_per_blk - 1) / nodes_per_blk;

    // build buckets + degrees
    hipMemsetAsync(cnt, 0, (size_t)n * sizeof(int), stream);
    fill_k<<<gb_E, tb, 0, stream>>>(src, dst, E, cnt, bkt);
    dinv_k<<<gb_n, tb, 0, stream>>>(cnt, dinv, n);

    // hop 1: x -> z1 (= x1 * dinv), hop 2: z1 -> x2
    gather_hop_k<true ><<<gb_g, tb, 0, stream>>>((const float2*)x,  cnt, bkt, dinv, (float2*)z1, n);
    gather_hop_k<false><<<gb_g, tb, 0, stream>>>((const float2*)z1, cnt, bkt, dinv, (float2*)x2, n);

    // fused MLP + log_softmax
    transform_k<<<(n + 63) / 64, 256, 0, stream>>>((const float4*)x2, W1, b1, W2, b2, out, n);
}

// Round 5
// 580.435 us; speedup vs baseline: 1.0097x; 1.0097x over previous
//
#include <hip/hip_runtime.h>
#include <math.h>

#define CAP 96   // max in-degree bucket capacity; deg ~ Poisson(16), P(deg>=96) ~ 1e-30

// ---------------- CSR-bucket build ----------------

__global__ void fill_k(const int* __restrict__ src, const int* __restrict__ dst,
                       int E, int* __restrict__ cnt, int* __restrict__ bkt) {
    int e = blockIdx.x * blockDim.x + threadIdx.x;
    if (e < E) {
        int d = dst[e];
        int pos = atomicAdd(&cnt[d], 1);
        if (pos < CAP) bkt[(size_t)d * CAP + pos] = src[e];
    }
}

__global__ void dinv_k(const int* __restrict__ cnt, float* __restrict__ dinv, int n) {
    int v = blockIdx.x * blockDim.x + threadIdx.x;
    if (v < n) dinv[v] = rsqrtf((float)(cnt[v] + 1));  // +1 self-loop
}

// ---------------- gather hop: one wave per node, float2 per lane ----------------
// SCALE_SRC=true  (hop1): out[v] = dinv[v]^2 * ( sum_e x[src]*dinv[src] + x[v]*dinv[v] )
// SCALE_SRC=false (hop2): out[v] = dinv[v]   * ( sum_e z[src]           + z[v]          )

template<bool SCALE_SRC>
__global__ __launch_bounds__(256) void gather_hop_k(
    const float2* __restrict__ xin,
    const int* __restrict__ cnt, const int* __restrict__ bkt,
    const float* __restrict__ dinv,
    float2* __restrict__ xout, int n)
{
    int v = blockIdx.x * (blockDim.x >> 6) + (threadIdx.x >> 6);
    if (v >= n) return;
    int l = threadIdx.x & 63;
    int c = cnt[v]; if (c > CAP) c = CAP;
    const int* __restrict__ b = bkt + (size_t)v * CAP;

    float2 acc = make_float2(0.f, 0.f);
    int i = 0;
    for (; i + 4 <= c; i += 4) {           // 4-edge unroll: memory-level parallelism
        int s0 = b[i], s1 = b[i + 1], s2 = b[i + 2], s3 = b[i + 3];
        float2 v0 = xin[(size_t)s0 * 64 + l];
        float2 v1 = xin[(size_t)s1 * 64 + l];
        float2 v2 = xin[(size_t)s2 * 64 + l];
        float2 v3 = xin[(size_t)s3 * 64 + l];
        if (SCALE_SRC) {
            float d0 = dinv[s0], d1 = dinv[s1], d2 = dinv[s2], d3 = dinv[s3];
            acc.x = fmaf(v0.x, d0, acc.x); acc.y = fmaf(v0.y, d0, acc.y);
            acc.x = fmaf(v1.x, d1, acc.x); acc.y = fmaf(v1.y, d1, acc.y);
            acc.x = fmaf(v2.x, d2, acc.x); acc.y = fmaf(v2.y, d2, acc.y);
            acc.x = fmaf(v3.x, d3, acc.x); acc.y = fmaf(v3.y, d3, acc.y);
        } else {
            acc.x += (v0.x + v1.x) + (v2.x + v3.x);
            acc.y += (v0.y + v1.y) + (v2.y + v3.y);
        }
    }
    for (; i < c; i++) {
        int s0 = b[i];
        float2 v0 = xin[(size_t)s0 * 64 + l];
        if (SCALE_SRC) {
            float d0 = dinv[s0];
            acc.x = fmaf(v0.x, d0, acc.x); acc.y = fmaf(v0.y, d0, acc.y);
        } else {
            acc.x += v0.x; acc.y += v0.y;
        }
    }

    float dv = dinv[v];
    float2 self = xin[(size_t)v * 64 + l];
    if (SCALE_SRC) {
        acc.x = fmaf(self.x, dv, acc.x);
        acc.y = fmaf(self.y, dv, acc.y);
        float s2 = dv * dv;
        acc.x *= s2; acc.y *= s2;
    } else {
        acc.x = (acc.x + self.x) * dv;
        acc.y = (acc.y + self.y) * dv;
    }
    xout[(size_t)v * 64 + l] = acc;
}

// ---------------- fused MLP + log_softmax ----------------
// 256 threads, 64 nodes/block. Register-tiled + SOFTWARE-PIPELINED W loads:
// w_next prefetched while FMAs consume w_cur -> ~128 FMA instrs of load slack.
__global__ __launch_bounds__(256, 4) void transform_k(
    const float4* __restrict__ x2,
    const float* __restrict__ W1, const float* __restrict__ b1,
    const float* __restrict__ W2, const float* __restrict__ b2,
    float* __restrict__ out, int n)
{
    __shared__ float xs[64][132];   // x tile, reused for h tile

    int t = threadIdx.x;
    int node0 = blockIdx.x * 64;

    // stage x tile: 64 rows x 32 float4
    for (int i = t; i < 64 * 32; i += 256) {
        int nn = i >> 5, j4 = i & 31;
        int node = node0 + nn;
        float4 v = make_float4(0.f, 0.f, 0.f, 0.f);
        if (node < n) v = x2[(size_t)node * 32 + j4];
        *(float4*)&xs[nn][j4 * 4] = v;
    }
    __syncthreads();

    // ---- layer 1: h[64][128] = relu(x @ W1^T + b1) ----
    int ftid = t & 31;          // 32 feature-groups of 4
    int ntid = t >> 5;          // 8 node-groups of 8
    float acc[8][4];
    {
        float4 bb = *(const float4*)&b1[ftid * 4];
#pragma unroll
        for (int i = 0; i < 8; i++) {
            acc[i][0] = bb.x; acc[i][1] = bb.y; acc[i][2] = bb.z; acc[i][3] = bb.w;
        }
    }
    {
        const float* w1r0 = W1 + (size_t)(ftid * 4 + 0) * 128;
        const float* w1r1 = W1 + (size_t)(ftid * 4 + 1) * 128;
        const float* w1r2 = W1 + (size_t)(ftid * 4 + 2) * 128;
        const float* w1r3 = W1 + (size_t)(ftid * 4 + 3) * 128;
        float4 wc0 = *(const float4*)&w1r0[0];
        float4 wc1 = *(const float4*)&w1r1[0];
        float4 wc2 = *(const float4*)&w1r2[0];
        float4 wc3 = *(const float4*)&w1r3[0];
        for (int k4 = 0; k4 < 32; k4++) {
            int kn = (k4 < 31) ? (k4 + 1) * 4 : 0;   // last iter reloads k=0 (unused)
            float4 wn0 = *(const float4*)&w1r0[kn];
            float4 wn1 = *(const float4*)&w1r1[kn];
            float4 wn2 = *(const float4*)&w1r2[kn];
            float4 wn3 = *(const float4*)&w1r3[kn];
#pragma unroll
            for (int i = 0; i < 8; i++) {
                float4 xv = *(const float4*)&xs[ntid * 8 + i][k4 * 4];  // 2 addrs/wave: broadcast
                acc[i][0] = fmaf(xv.x, wc0.x, acc[i][0]);
                acc[i][0] = fmaf(xv.y, wc0.y, acc[i][0]);
                acc[i][0] = fmaf(xv.z, wc0.z, acc[i][0]);
                acc[i][0] = fmaf(xv.w, wc0.w, acc[i][0]);
                acc[i][1] = fmaf(xv.x, wc1.x, acc[i][1]);
                acc[i][1] = fmaf(xv.y, wc1.y, acc[i][1]);
                acc[i][1] = fmaf(xv.z, wc1.z, acc[i][1]);
                acc[i][1] = fmaf(xv.w, wc1.w, acc[i][1]);
                acc[i][2] = fmaf(xv.x, wc2.x, acc[i][2]);
                acc[i][2] = fmaf(xv.y, wc2.y, acc[i][2]);
                acc[i][2] = fmaf(xv.z, wc2.z, acc[i][2]);
                acc[i][2] = fmaf(xv.w, wc2.w, acc[i][2]);
                acc[i][3] = fmaf(xv.x, wc3.x, acc[i][3]);
                acc[i][3] = fmaf(xv.y, wc3.y, acc[i][3]);
                acc[i][3] = fmaf(xv.z, wc3.z, acc[i][3]);
                acc[i][3] = fmaf(xv.w, wc3.w, acc[i][3]);
            }
            wc0 = wn0; wc1 = wn1; wc2 = wn2; wc3 = wn3;
        }
    }
    __syncthreads();   // all x reads done; safe to overwrite with h
#pragma unroll
    for (int i = 0; i < 8; i++) {
        float4 h4 = make_float4(fmaxf(acc[i][0], 0.f), fmaxf(acc[i][1], 0.f),
                                fmaxf(acc[i][2], 0.f), fmaxf(acc[i][3], 0.f));
        *(float4*)&xs[ntid * 8 + i][ftid * 4] = h4;
    }
    __syncthreads();

    // ---- layer 2: logits[64][64] = h @ W2^T + b2 ----
    int ltid = t & 15;          // 16 logit-groups of 4
    int ntid2 = t >> 4;         // 16 node-groups of 4
    float acc2[4][4];
    {
        float4 bb = *(const float4*)&b2[ltid * 4];
#pragma unroll
        for (int i = 0; i < 4; i++) {
            acc2[i][0] = bb.x; acc2[i][1] = bb.y; acc2[i][2] = bb.z; acc2[i][3] = bb.w;
        }
    }
    {
        const float* w2r0 = W2 + (size_t)(ltid * 4 + 0) * 128;
        const float* w2r1 = W2 + (size_t)(ltid * 4 + 1) * 128;
        const float* w2r2 = W2 + (size_t)(ltid * 4 + 2) * 128;
        const float* w2r3 = W2 + (size_t)(ltid * 4 + 3) * 128;
        float4 wc0 = *(const float4*)&w2r0[0];
        float4 wc1 = *(const float4*)&w2r1[0];
        float4 wc2 = *(const float4*)&w2r2[0];
        float4 wc3 = *(const float4*)&w2r3[0];
        for (int k4 = 0; k4 < 32; k4++) {
            int kn = (k4 < 31) ? (k4 + 1) * 4 : 0;
            float4 wn0 = *(const float4*)&w2r0[kn];
            float4 wn1 = *(const float4*)&w2r1[kn];
            float4 wn2 = *(const float4*)&w2r2[kn];
            float4 wn3 = *(const float4*)&w2r3[kn];
#pragma unroll
            for (int i = 0; i < 4; i++) {
                float4 hv = *(const float4*)&xs[ntid2 * 4 + i][k4 * 4];
                acc2[i][0] = fmaf(hv.x, wc0.x, acc2[i][0]);
                acc2[i][0] = fmaf(hv.y, wc0.y, acc2[i][0]);
                acc2[i][0] = fmaf(hv.z, wc0.z, acc2[i][0]);
                acc2[i][0] = fmaf(hv.w, wc0.w, acc2[i][0]);
                acc2[i][1] = fmaf(hv.x, wc1.x, acc2[i][1]);
                acc2[i][1] = fmaf(hv.y, wc1.y, acc2[i][1]);
                acc2[i][1] = fmaf(hv.z, wc1.z, acc2[i][1]);
                acc2[i][1] = fmaf(hv.w, wc1.w, acc2[i][1]);
                acc2[i][2] = fmaf(hv.x, wc2.x, acc2[i][2]);
                acc2[i][2] = fmaf(hv.y, wc2.y, acc2[i][2]);
                acc2[i][2] = fmaf(hv.z, wc2.z, acc2[i][2]);
                acc2[i][2] = fmaf(hv.w, wc2.w, acc2[i][2]);
                acc2[i][3] = fmaf(hv.x, wc3.x, acc2[i][3]);
                acc2[i][3] = fmaf(hv.y, wc3.y, acc2[i][3]);
                acc2[i][3] = fmaf(hv.z, wc3.z, acc2[i][3]);
                acc2[i][3] = fmaf(hv.w, wc3.w, acc2[i][3]);
            }
            wc0 = wn0; wc1 = wn1; wc2 = wn2; wc3 = wn3;
        }
    }

    // ---- log_softmax per node across the 16 threads holding its 64 logits ----
#pragma unroll
    for (int i = 0; i < 4; i++) {
        float m = fmaxf(fmaxf(acc2[i][0], acc2[i][1]), fmaxf(acc2[i][2], acc2[i][3]));
        m = fmaxf(m, __shfl_xor(m, 1, 16));
        m = fmaxf(m, __shfl_xor(m, 2, 16));
        m = fmaxf(m, __shfl_xor(m, 4, 16));
        m = fmaxf(m, __shfl_xor(m, 8, 16));
        float s = __expf(acc2[i][0] - m) + __expf(acc2[i][1] - m) +
                  __expf(acc2[i][2] - m) + __expf(acc2[i][3] - m);
        s += __shfl_xor(s, 1, 16);
        s += __shfl_xor(s, 2, 16);
        s += __shfl_xor(s, 4, 16);
        s += __shfl_xor(s, 8, 16);
        float lse = m + __logf(s);
        int node = node0 + ntid2 * 4 + i;
        if (node < n) {
            float4 o = make_float4(acc2[i][0] - lse, acc2[i][1] - lse,
                                   acc2[i][2] - lse, acc2[i][3] - lse);
            *(float4*)&out[(size_t)node * 64 + ltid * 4] = o;
        }
    }
}

// ---------------- launch ----------------

static inline size_t align256(size_t x) { return (x + 255) & ~(size_t)255; }

extern "C" void kernel_launch(void* const* d_in, const int* in_sizes, int n_in,
                              void* d_out, int out_size, void* d_ws, size_t ws_size,
                              hipStream_t stream) {
    const float* x  = (const float*)d_in[0];
    const int*   ei = (const int*)d_in[1];
    const float* W1 = (const float*)d_in[2];
    const float* b1 = (const float*)d_in[3];
    const float* W2 = (const float*)d_in[4];
    const float* b2 = (const float*)d_in[5];
    float* out = (float*)d_out;

    int n = in_sizes[0] / 128;        // 100000
    int E = in_sizes[1] / 2;          // 1600000
    const int* src = ei;
    const int* dst = ei + E;

    // workspace layout
    char* w = (char*)d_ws;
    size_t off = 0;
    int*   cnt  = (int*)(w + off);   off += align256((size_t)n * sizeof(int));
    float* dinv = (float*)(w + off); off += align256((size_t)n * sizeof(float));
    int*   bkt  = (int*)(w + off);   off += align256((size_t)n * CAP * sizeof(int));
    float* z1   = (float*)(w + off); off += align256((size_t)n * 128 * sizeof(float));
    float* x2   = (float*)(w + off);

    int tb = 256;
    int gb_n = (n + tb - 1) / tb;
    int gb_E = (E + tb - 1) / tb;
    int nodes_per_blk = tb / 64;
    int gb_g = (n + nodes_per_blk - 1) / nodes_per_blk;

    // build buckets + degrees
    hipMemsetAsync(cnt, 0, (size_t)n * sizeof(int), stream);
    fill_k<<<gb_E, tb, 0, stream>>>(src, dst, E, cnt, bkt);
    dinv_k<<<gb_n, tb, 0, stream>>>(cnt, dinv, n);

    // hop 1: x -> z1 (= x1 * dinv), hop 2: z1 -> x2
    gather_hop_k<true ><<<gb_g, tb, 0, stream>>>((const float2*)x,  cnt, bkt, dinv, (float2*)z1, n);
    gather_hop_k<false><<<gb_g, tb, 0, stream>>>((const float2*)z1, cnt, bkt, dinv, (float2*)x2, n);

    // fused MLP + log_softmax
    transform_k<<<(n + 63) / 64, 256, 0, stream>>>((const float4*)x2, W1, b1, W2, b2, out, n);
}

// Round 6
// 340.905 us; speedup vs baseline: 1.7191x; 1.7026x over previous
//
#include <hip/hip_runtime.h>
#include <math.h>

#define CAP 64   // max in-degree bucket; deg ~ Poisson(16), P(deg>=64) ~ 1e-20

typedef __attribute__((ext_vector_type(8))) short short8;   // 8 bf16 = 4 VGPR (MFMA A/B frag)
typedef __attribute__((ext_vector_type(4))) float f32x4;    // MFMA C/D frag

static __device__ inline unsigned short f2bf(float f) {     // RNE f32 -> bf16
    unsigned int u = __float_as_uint(f);
    u += 0x7fffu + ((u >> 16) & 1u);
    return (unsigned short)(u >> 16);
}
static __device__ inline float bf_lo(unsigned int u) { return __uint_as_float(u << 16); }
static __device__ inline float bf_hi(unsigned int u) { return __uint_as_float(u & 0xffff0000u); }
static __device__ inline unsigned int pack2(float lo, float hi) {
    return ((unsigned int)f2bf(hi) << 16) | (unsigned int)f2bf(lo);
}

// ---------------- CSR-bucket build ----------------

__global__ void fill_k(const int* __restrict__ src, const int* __restrict__ dst,
                       int E, int* __restrict__ cnt, int* __restrict__ bkt) {
    int e = blockIdx.x * blockDim.x + threadIdx.x;
    if (e < E) {
        int d = dst[e];
        int pos = atomicAdd(&cnt[d], 1);
        if (pos < CAP) bkt[(size_t)d * CAP + pos] = src[e];
    }
}

__global__ void dinv_k(const int* __restrict__ cnt, float* __restrict__ dinv, int n) {
    int v = blockIdx.x * blockDim.x + threadIdx.x;
    if (v < n) dinv[v] = rsqrtf((float)(cnt[v] + 1));  // +1 self-loop
}

// ---------------- converters ----------------

// xb[v][f] = bf16( x[v][f] * dinv[v] ); one uint (2 feats) per thread
__global__ void conv_x_k(const float2* __restrict__ x, const float* __restrict__ dinv,
                         unsigned int* __restrict__ xb, int n) {
    int i = blockIdx.x * blockDim.x + threadIdx.x;   // over n*64 float2s
    if (i < n * 64) {
        float sc = dinv[i >> 6];
        float2 v = x[i];
        xb[i] = pack2(v.x * sc, v.y * sc);
    }
}

// generic f32 -> bf16 pair converter (for W1, W2)
__global__ void conv_w_k(const float2* __restrict__ in, unsigned int* __restrict__ out, int n2) {
    int i = blockIdx.x * blockDim.x + threadIdx.x;
    if (i < n2) {
        float2 v = in[i];
        out[i] = pack2(v.x, v.y);
    }
}

// ---------------- gather hop (bf16 rows), one wave per node ----------------
// out[v] = scale_v * ( sum_{s in bkt[v]} in[s] + in[v] ),  scale = SQ ? dinv^2 : dinv

template<bool SQ>
__global__ __launch_bounds__(256) void gather_b_k(
    const unsigned int* __restrict__ xin,   // [n][64] bf16-pairs
    const int* __restrict__ cnt, const int* __restrict__ bkt,
    const float* __restrict__ dinv,
    unsigned int* __restrict__ xout, int n)
{
    int v = blockIdx.x * 4 + (threadIdx.x >> 6);
    if (v >= n) return;
    int l = threadIdx.x & 63;
    int c = cnt[v]; if (c > CAP) c = CAP;
    const int* __restrict__ b = bkt + (size_t)v * CAP;

    float ax = 0.f, ay = 0.f;
    int i = 0;
    for (; i + 4 <= c; i += 4) {
        int s0 = b[i], s1 = b[i+1], s2 = b[i+2], s3 = b[i+3];
        unsigned int u0 = xin[(size_t)s0 * 64 + l];
        unsigned int u1 = xin[(size_t)s1 * 64 + l];
        unsigned int u2 = xin[(size_t)s2 * 64 + l];
        unsigned int u3 = xin[(size_t)s3 * 64 + l];
        ax += (bf_lo(u0) + bf_lo(u1)) + (bf_lo(u2) + bf_lo(u3));
        ay += (bf_hi(u0) + bf_hi(u1)) + (bf_hi(u2) + bf_hi(u3));
    }
    for (; i < c; i++) {
        unsigned int u0 = xin[(size_t)b[i] * 64 + l];
        ax += bf_lo(u0);
        ay += bf_hi(u0);
    }
    unsigned int us = xin[(size_t)v * 64 + l];   // self-loop term
    ax += bf_lo(us);
    ay += bf_hi(us);

    float dv = dinv[v];
    float sc = SQ ? dv * dv : dv;
    xout[(size_t)v * 64 + l] = pack2(ax * sc, ay * sc);
}

// ---------------- fused MLP + log_softmax via MFMA ----------------
// 256 threads = 4 waves; 64 nodes/block (16 per wave).
// GEMM1: H[64x128] = X[64x128] @ W1^T, GEMM2: L[64x64] = H @ W2^T.
// mfma_f32_16x16x32_bf16 layouts: A: lane holds A[l&15][(l>>4)*8+j];
// B: lane holds B[(l>>4)*8+j][l&15]; D: lane holds D[(l>>4)*4+r][l&15].
__global__ __launch_bounds__(256) void transform_mfma_k(
    const unsigned short* __restrict__ x2b,   // [n][128] bf16
    const unsigned short* __restrict__ w1b,   // [128][128] bf16 (row-major [o][k])
    const float* __restrict__ b1,
    const unsigned short* __restrict__ w2b,   // [64][128] bf16
    const float* __restrict__ b2,
    float* __restrict__ out, int n)
{
    __shared__ __align__(16) unsigned short Hs[64][152];  // 304B row stride: 2-way-free reads

    int t = threadIdx.x;
    int w = t >> 6;        // wave 0..3 -> node rows w*16..w*16+15
    int l = t & 63;
    int lg = l >> 4;       // lane group 0..3
    int ll = l & 15;
    int node0 = blockIdx.x * 64;

    // ---- A frags for GEMM1: X rows (clamped; invalid rows discarded at write) ----
    int nrow = node0 + w * 16 + ll;
    int crow = nrow < n ? nrow : (n - 1);
    const unsigned short* xrow = x2b + (size_t)crow * 128 + lg * 8;
    short8 a[4];
#pragma unroll
    for (int kb = 0; kb < 4; kb++)
        a[kb] = *(const short8*)(xrow + kb * 32);

    // ---- GEMM1: 8 n-tiles x 4 k-blocks ----
    f32x4 acc[8];
#pragma unroll
    for (int nt = 0; nt < 8; nt++) {
        float bv = b1[nt * 16 + ll];
        acc[nt][0] = bv; acc[nt][1] = bv; acc[nt][2] = bv; acc[nt][3] = bv;
    }
#pragma unroll
    for (int nt = 0; nt < 8; nt++) {
        const unsigned short* wrow = w1b + (size_t)(nt * 16 + ll) * 128 + lg * 8;
#pragma unroll
        for (int kb = 0; kb < 4; kb++) {
            short8 bf = *(const short8*)(wrow + kb * 32);
            acc[nt] = __builtin_amdgcn_mfma_f32_16x16x32_bf16(a[kb], bf, acc[nt], 0, 0, 0);
        }
    }

    // ---- relu -> bf16 -> LDS (each wave writes/reads only its own 16-row slice) ----
#pragma unroll
    for (int nt = 0; nt < 8; nt++) {
#pragma unroll
        for (int r = 0; r < 4; r++) {
            float hv = fmaxf(acc[nt][r], 0.f);
            Hs[w * 16 + lg * 4 + r][nt * 16 + ll] = f2bf(hv);
        }
    }
    // intra-wave LDS write->read: lgkmcnt ordering suffices (no barrier needed)

    // ---- A frags for GEMM2 from Hs ----
    short8 ha[4];
#pragma unroll
    for (int kb = 0; kb < 4; kb++)
        ha[kb] = *(const short8*)&Hs[w * 16 + ll][kb * 32 + lg * 8];

    // ---- GEMM2: 4 n-tiles x 4 k-blocks ----
    f32x4 acc2[4];
#pragma unroll
    for (int nt = 0; nt < 4; nt++) {
        float bv = b2[nt * 16 + ll];
        acc2[nt][0] = bv; acc2[nt][1] = bv; acc2[nt][2] = bv; acc2[nt][3] = bv;
        const unsigned short* wrow = w2b + (size_t)(nt * 16 + ll) * 128 + lg * 8;
#pragma unroll
        for (int kb = 0; kb < 4; kb++) {
            short8 bf = *(const short8*)(wrow + kb * 32);
            acc2[nt] = __builtin_amdgcn_mfma_f32_16x16x32_bf16(ha[kb], bf, acc2[nt], 0, 0, 0);
        }
    }

    // ---- log_softmax per node row; lane holds rows (lg*4+r), cols nt*16+ll ----
#pragma unroll
    for (int r = 0; r < 4; r++) {
        float m = fmaxf(fmaxf(acc2[0][r], acc2[1][r]), fmaxf(acc2[2][r], acc2[3][r]));
        m = fmaxf(m, __shfl_xor(m, 1));
        m = fmaxf(m, __shfl_xor(m, 2));
        m = fmaxf(m, __shfl_xor(m, 4));
        m = fmaxf(m, __shfl_xor(m, 8));
        float s = __expf(acc2[0][r] - m) + __expf(acc2[1][r] - m) +
                  __expf(acc2[2][r] - m) + __expf(acc2[3][r] - m);
        s += __shfl_xor(s, 1);
        s += __shfl_xor(s, 2);
        s += __shfl_xor(s, 4);
        s += __shfl_xor(s, 8);
        float lse = m + __logf(s);
        int node = node0 + w * 16 + lg * 4 + r;
        if (node < n) {
#pragma unroll
            for (int nt = 0; nt < 4; nt++)
                out[(size_t)node * 64 + nt * 16 + ll] = acc2[nt][r] - lse;
        }
    }
}

// ---------------- launch ----------------

static inline size_t align256(size_t x) { return (x + 255) & ~(size_t)255; }

extern "C" void kernel_launch(void* const* d_in, const int* in_sizes, int n_in,
                              void* d_out, int out_size, void* d_ws, size_t ws_size,
                              hipStream_t stream) {
    const float* x  = (const float*)d_in[0];
    const int*   ei = (const int*)d_in[1];
    const float* W1 = (const float*)d_in[2];
    const float* b1 = (const float*)d_in[3];
    const float* W2 = (const float*)d_in[4];
    const float* b2 = (const float*)d_in[5];
    float* out = (float*)d_out;

    int n = in_sizes[0] / 128;        // 100000
    int E = in_sizes[1] / 2;          // 1600000
    const int* src = ei;
    const int* dst = ei + E;

    // workspace layout
    char* w = (char*)d_ws;
    size_t off = 0;
    int*          cnt  = (int*)(w + off);          off += align256((size_t)n * sizeof(int));
    float*        dinv = (float*)(w + off);        off += align256((size_t)n * sizeof(float));
    int*          bkt  = (int*)(w + off);          off += align256((size_t)n * CAP * sizeof(int));
    unsigned int* xb   = (unsigned int*)(w + off); off += align256((size_t)n * 64 * sizeof(unsigned int));
    unsigned int* z1b  = (unsigned int*)(w + off); off += align256((size_t)n * 64 * sizeof(unsigned int));
    unsigned int* x2b  = (unsigned int*)(w + off); off += align256((size_t)n * 64 * sizeof(unsigned int));
    unsigned int* w1b  = (unsigned int*)(w + off); off += align256((size_t)128 * 64 * sizeof(unsigned int));
    unsigned int* w2b  = (unsigned int*)(w + off);

    int tb = 256;
    int gb_n = (n + tb - 1) / tb;
    int gb_E = (E + tb - 1) / tb;
    int gb_x = (n * 64 + tb - 1) / tb;
    int gb_g = (n + 3) / 4;

    // degrees + buckets
    hipMemsetAsync(cnt, 0, (size_t)n * sizeof(int), stream);
    fill_k<<<gb_E, tb, 0, stream>>>(src, dst, E, cnt, bkt);
    dinv_k<<<gb_n, tb, 0, stream>>>(cnt, dinv, n);

    // converters
    conv_x_k<<<gb_x, tb, 0, stream>>>((const float2*)x, dinv, xb, n);
    conv_w_k<<<(128 * 64 + tb - 1) / tb, tb, 0, stream>>>((const float2*)W1, w1b, 128 * 64);
    conv_w_k<<<(64 * 64 + tb - 1) / tb, tb, 0, stream>>>((const float2*)W2, w2b, 64 * 64);

    // hop 1: xb -> z1b (scale dinv^2), hop 2: z1b -> x2b (scale dinv)
    gather_b_k<true ><<<gb_g, tb, 0, stream>>>(xb,  cnt, bkt, dinv, z1b, n);
    gather_b_k<false><<<gb_g, tb, 0, stream>>>(z1b, cnt, bkt, dinv, x2b, n);

    // fused MFMA MLP + log_softmax
    transform_mfma_k<<<(n + 63) / 64, 256, 0, stream>>>(
        (const unsigned short*)x2b, (const unsigned short*)w1b, b1,
        (const unsigned short*)w2b, b2, out, n);
}

// Round 7
// 326.455 us; speedup vs baseline: 1.7952x; 1.0443x over previous
//
#include <hip/hip_runtime.h>
#include <math.h>

#define CAP 64      // max in-degree bucket; deg ~ Poisson(16), P(deg>=64) ~ 1e-20
#define NSLICE 8    // dst-slices for the fill: 12.5k nodes -> 3.2MB bucket region (L2-hot)

typedef __attribute__((ext_vector_type(8))) short short8;   // 8 bf16 = 4 VGPR (MFMA A/B frag)
typedef __attribute__((ext_vector_type(4))) float f32x4;    // MFMA C/D frag

static __device__ inline unsigned short f2bf(float f) {     // RNE f32 -> bf16
    unsigned int u = __float_as_uint(f);
    u += 0x7fffu + ((u >> 16) & 1u);
    return (unsigned short)(u >> 16);
}
static __device__ inline float bf_lo(unsigned int u) { return __uint_as_float(u << 16); }
static __device__ inline float bf_hi(unsigned int u) { return __uint_as_float(u & 0xffff0000u); }
static __device__ inline unsigned int pack2(float lo, float hi) {
    return ((unsigned int)f2bf(hi) << 16) | (unsigned int)f2bf(lo);
}

// ---------------- CSR-bucket build, dst-sliced for L2-resident scatter ----------------
// Pass processes only edges with dst in [lo,hi): bucket slice = (hi-lo)*CAP*4B ~ 3.2MB
// stays in L2 so the ~16 stores per bucket line coalesce before one write-back.

__global__ void fill_slice_k(const int* __restrict__ dst, const int* __restrict__ src,
                             int E, int lo, int hi,
                             int* __restrict__ cnt, int* __restrict__ bkt) {
    int base = (blockIdx.x * blockDim.x + threadIdx.x) * 4;
    if (base >= E) return;
    if (base + 4 <= E) {
        int4 d4 = *(const int4*)(dst + base);
#pragma unroll
        for (int j = 0; j < 4; j++) {
            int d = (&d4.x)[j];
            if (d >= lo && d < hi) {
                int pos = atomicAdd(&cnt[d], 1);
                if (pos < CAP) bkt[(size_t)d * CAP + pos] = src[base + j];
            }
        }
    } else {
        for (int e = base; e < E; e++) {
            int d = dst[e];
            if (d >= lo && d < hi) {
                int pos = atomicAdd(&cnt[d], 1);
                if (pos < CAP) bkt[(size_t)d * CAP + pos] = src[e];
            }
        }
    }
}

__global__ void dinv_k(const int* __restrict__ cnt, float* __restrict__ dinv, int n) {
    int v = blockIdx.x * blockDim.x + threadIdx.x;
    if (v < n) dinv[v] = rsqrtf((float)(cnt[v] + 1));  // +1 self-loop
}

// ---------------- converters ----------------

// xb[v][f] = bf16( x[v][f] * dinv[v] ); one uint (2 feats) per thread
__global__ void conv_x_k(const float2* __restrict__ x, const float* __restrict__ dinv,
                         unsigned int* __restrict__ xb, int n) {
    int i = blockIdx.x * blockDim.x + threadIdx.x;   // over n*64 float2s
    if (i < n * 64) {
        float sc = dinv[i >> 6];
        float2 v = x[i];
        xb[i] = pack2(v.x * sc, v.y * sc);
    }
}

// generic f32 -> bf16 pair converter (for W1, W2)
__global__ void conv_w_k(const float2* __restrict__ in, unsigned int* __restrict__ out, int n2) {
    int i = blockIdx.x * blockDim.x + threadIdx.x;
    if (i < n2) {
        float2 v = in[i];
        out[i] = pack2(v.x, v.y);
    }
}

// ---------------- gather hop (bf16 rows), one wave per node ----------------
// out[v] = scale_v * ( sum_{s in bkt[v]} in[s] + in[v] ),  scale = SQ ? dinv^2 : dinv

template<bool SQ>
__global__ __launch_bounds__(256) void gather_b_k(
    const unsigned int* __restrict__ xin,   // [n][64] bf16-pairs
    const int* __restrict__ cnt, const int* __restrict__ bkt,
    const float* __restrict__ dinv,
    unsigned int* __restrict__ xout, int n)
{
    int v = blockIdx.x * 4 + (threadIdx.x >> 6);
    if (v >= n) return;
    int l = threadIdx.x & 63;
    int c = cnt[v]; if (c > CAP) c = CAP;
    const int* __restrict__ b = bkt + (size_t)v * CAP;

    float ax = 0.f, ay = 0.f;
    int i = 0;
    for (; i + 4 <= c; i += 4) {
        int s0 = b[i], s1 = b[i+1], s2 = b[i+2], s3 = b[i+3];
        unsigned int u0 = xin[(size_t)s0 * 64 + l];
        unsigned int u1 = xin[(size_t)s1 * 64 + l];
        unsigned int u2 = xin[(size_t)s2 * 64 + l];
        unsigned int u3 = xin[(size_t)s3 * 64 + l];
        ax += (bf_lo(u0) + bf_lo(u1)) + (bf_lo(u2) + bf_lo(u3));
        ay += (bf_hi(u0) + bf_hi(u1)) + (bf_hi(u2) + bf_hi(u3));
    }
    for (; i < c; i++) {
        unsigned int u0 = xin[(size_t)b[i] * 64 + l];
        ax += bf_lo(u0);
        ay += bf_hi(u0);
    }
    unsigned int us = xin[(size_t)v * 64 + l];   // self-loop term
    ax += bf_lo(us);
    ay += bf_hi(us);

    float dv = dinv[v];
    float sc = SQ ? dv * dv : dv;
    xout[(size_t)v * 64 + l] = pack2(ax * sc, ay * sc);
}

// ---------------- fused MLP + log_softmax via MFMA ----------------
// 256 threads = 4 waves; 64 nodes/block (16 per wave).
__global__ __launch_bounds__(256) void transform_mfma_k(
    const unsigned short* __restrict__ x2b,   // [n][128] bf16
    const unsigned short* __restrict__ w1b,   // [128][128] bf16 (row-major [o][k])
    const float* __restrict__ b1,
    const unsigned short* __restrict__ w2b,   // [64][128] bf16
    const float* __restrict__ b2,
    float* __restrict__ out, int n)
{
    __shared__ __align__(16) unsigned short Hs[64][152];  // 304B row stride

    int t = threadIdx.x;
    int w = t >> 6;        // wave 0..3 -> node rows w*16..w*16+15
    int l = t & 63;
    int lg = l >> 4;       // lane group 0..3
    int ll = l & 15;
    int node0 = blockIdx.x * 64;

    // ---- A frags for GEMM1: X rows (clamped; invalid rows discarded at write) ----
    int nrow = node0 + w * 16 + ll;
    int crow = nrow < n ? nrow : (n - 1);
    const unsigned short* xrow = x2b + (size_t)crow * 128 + lg * 8;
    short8 a[4];
#pragma unroll
    for (int kb = 0; kb < 4; kb++)
        a[kb] = *(const short8*)(xrow + kb * 32);

    // ---- GEMM1: 8 n-tiles x 4 k-blocks ----
    f32x4 acc[8];
#pragma unroll
    for (int nt = 0; nt < 8; nt++) {
        float bv = b1[nt * 16 + ll];
        acc[nt][0] = bv; acc[nt][1] = bv; acc[nt][2] = bv; acc[nt][3] = bv;
    }
#pragma unroll
    for (int nt = 0; nt < 8; nt++) {
        const unsigned short* wrow = w1b + (size_t)(nt * 16 + ll) * 128 + lg * 8;
#pragma unroll
        for (int kb = 0; kb < 4; kb++) {
            short8 bf = *(const short8*)(wrow + kb * 32);
            acc[nt] = __builtin_amdgcn_mfma_f32_16x16x32_bf16(a[kb], bf, acc[nt], 0, 0, 0);
        }
    }

    // ---- relu -> bf16 -> LDS (each wave writes/reads only its own 16-row slice) ----
#pragma unroll
    for (int nt = 0; nt < 8; nt++) {
#pragma unroll
        for (int r = 0; r < 4; r++) {
            float hv = fmaxf(acc[nt][r], 0.f);
            Hs[w * 16 + lg * 4 + r][nt * 16 + ll] = f2bf(hv);
        }
    }
    // intra-wave LDS write->read: lgkmcnt ordering suffices (no barrier needed)

    // ---- A frags for GEMM2 from Hs ----
    short8 ha[4];
#pragma unroll
    for (int kb = 0; kb < 4; kb++)
        ha[kb] = *(const short8*)&Hs[w * 16 + ll][kb * 32 + lg * 8];

    // ---- GEMM2: 4 n-tiles x 4 k-blocks ----
    f32x4 acc2[4];
#pragma unroll
    for (int nt = 0; nt < 4; nt++) {
        float bv = b2[nt * 16 + ll];
        acc2[nt][0] = bv; acc2[nt][1] = bv; acc2[nt][2] = bv; acc2[nt][3] = bv;
        const unsigned short* wrow = w2b + (size_t)(nt * 16 + ll) * 128 + lg * 8;
#pragma unroll
        for (int kb = 0; kb < 4; kb++) {
            short8 bf = *(const short8*)(wrow + kb * 32);
            acc2[nt] = __builtin_amdgcn_mfma_f32_16x16x32_bf16(ha[kb], bf, acc2[nt], 0, 0, 0);
        }
    }

    // ---- log_softmax per node row; lane holds rows (lg*4+r), cols nt*16+ll ----
#pragma unroll
    for (int r = 0; r < 4; r++) {
        float m = fmaxf(fmaxf(acc2[0][r], acc2[1][r]), fmaxf(acc2[2][r], acc2[3][r]));
        m = fmaxf(m, __shfl_xor(m, 1));
        m = fmaxf(m, __shfl_xor(m, 2));
        m = fmaxf(m, __shfl_xor(m, 4));
        m = fmaxf(m, __shfl_xor(m, 8));
        float s = __expf(acc2[0][r] - m) + __expf(acc2[1][r] - m) +
                  __expf(acc2[2][r] - m) + __expf(acc2[3][r] - m);
        s += __shfl_xor(s, 1);
        s += __shfl_xor(s, 2);
        s += __shfl_xor(s, 4);
        s += __shfl_xor(s, 8);
        float lse = m + __logf(s);
        int node = node0 + w * 16 + lg * 4 + r;
        if (node < n) {
#pragma unroll
            for (int nt = 0; nt < 4; nt++)
                out[(size_t)node * 64 + nt * 16 + ll] = acc2[nt][r] - lse;
        }
    }
}

// ---------------- launch ----------------

static inline size_t align256(size_t x) { return (x + 255) & ~(size_t)255; }

extern "C" void kernel_launch(void* const* d_in, const int* in_sizes, int n_in,
                              void* d_out, int out_size, void* d_ws, size_t ws_size,
                              hipStream_t stream) {
    const float* x  = (const float*)d_in[0];
    const int*   ei = (const int*)d_in[1];
    const float* W1 = (const float*)d_in[2];
    const float* b1 = (const float*)d_in[3];
    const float* W2 = (const float*)d_in[4];
    const float* b2 = (const float*)d_in[5];
    float* out = (float*)d_out;

    int n = in_sizes[0] / 128;        // 100000
    int E = in_sizes[1] / 2;          // 1600000
    const int* src = ei;
    const int* dst = ei + E;

    // workspace layout
    char* w = (char*)d_ws;
    size_t off = 0;
    int*          cnt  = (int*)(w + off);          off += align256((size_t)n * sizeof(int));
    float*        dinv = (float*)(w + off);        off += align256((size_t)n * sizeof(float));
    int*          bkt  = (int*)(w + off);          off += align256((size_t)n * CAP * sizeof(int));
    unsigned int* xb   = (unsigned int*)(w + off); off += align256((size_t)n * 64 * sizeof(unsigned int));
    unsigned int* z1b  = (unsigned int*)(w + off); off += align256((size_t)n * 64 * sizeof(unsigned int));
    unsigned int* x2b  = (unsigned int*)(w + off); off += align256((size_t)n * 64 * sizeof(unsigned int));
    unsigned int* w1b  = (unsigned int*)(w + off); off += align256((size_t)128 * 64 * sizeof(unsigned int));
    unsigned int* w2b  = (unsigned int*)(w + off);

    int tb = 256;
    int gb_n = (n + tb - 1) / tb;
    int gb_f = (E + tb * 4 - 1) / (tb * 4);   // 4 edges/thread
    int gb_x = (n * 64 + tb - 1) / tb;
    int gb_g = (n + 3) / 4;

    // degrees + buckets: dst-sliced passes keep the scatter region L2-resident
    hipMemsetAsync(cnt, 0, (size_t)n * sizeof(int), stream);
    int sl = (n + NSLICE - 1) / NSLICE;       // 12500
    for (int s = 0; s < NSLICE; s++) {
        int lo = s * sl;
        int hi = lo + sl < n ? lo + sl : n;
        if (lo >= hi) break;
        fill_slice_k<<<gb_f, tb, 0, stream>>>(dst, src, E, lo, hi, cnt, bkt);
    }
    dinv_k<<<gb_n, tb, 0, stream>>>(cnt, dinv, n);

    // converters
    conv_x_k<<<gb_x, tb, 0, stream>>>((const float2*)x, dinv, xb, n);
    conv_w_k<<<(128 * 64 + tb - 1) / tb, tb, 0, stream>>>((const float2*)W1, w1b, 128 * 64);
    conv_w_k<<<(64 * 64 + tb - 1) / tb, tb, 0, stream>>>((const float2*)W2, w2b, 64 * 64);

    // hop 1: xb -> z1b (scale dinv^2), hop 2: z1b -> x2b (scale dinv)
    gather_b_k<true ><<<gb_g, tb, 0, stream>>>(xb,  cnt, bkt, dinv, z1b, n);
    gather_b_k<false><<<gb_g, tb, 0, stream>>>(z1b, cnt, bkt, dinv, x2b, n);

    // fused MFMA MLP + log_softmax
    transform_mfma_k<<<(n + 63) / 64, 256, 0, stream>>>(
        (const unsigned short*)x2b, (const unsigned short*)w1b, b1,
        (const unsigned short*)w2b, b2, out, n);
}

// Round 9
// 275.278 us; speedup vs baseline: 2.1289x; 1.1859x over previous
//
#include <hip/hip_runtime.h>
#include <math.h>

#define CAP 64      // max in-degree bucket; deg ~ Poisson(16), P(deg>=64) ~ 1e-20
#define NSLICE 8    // dst-slices == XCD count; slice = blockIdx%8 -> one XCD owns each slice

typedef __attribute__((ext_vector_type(8))) short short8;   // 8 bf16 = 4 VGPR (MFMA A/B frag)
typedef __attribute__((ext_vector_type(4))) float f32x4;    // MFMA C/D frag
typedef __attribute__((ext_vector_type(4))) int int4v;      // clang vector (nontemporal-compatible)

static __device__ inline unsigned short f2bf(float f) {     // RNE f32 -> bf16
    unsigned int u = __float_as_uint(f);
    u += 0x7fffu + ((u >> 16) & 1u);
    return (unsigned short)(u >> 16);
}
static __device__ inline float bf_lo(unsigned int u) { return __uint_as_float(u << 16); }
static __device__ inline float bf_hi(unsigned int u) { return __uint_as_float(u & 0xffff0000u); }
static __device__ inline unsigned int pack2(float lo, float hi) {
    return ((unsigned int)f2bf(hi) << 16) | (unsigned int)f2bf(lo);
}

// ---------------- CSR-bucket build, XCD-sliced in ONE launch ----------------
// slice s = blockIdx%8; under round-robin block->XCD dispatch all stores to
// slice s's cnt/bkt lines come from ONE XCD -> single dirty copy per line,
// no cross-XCD write-back amplification. Every slice is covered by
// construction regardless of the actual mapping (correctness-independent).

__global__ __launch_bounds__(256) void fill_swz_k(
    const int* __restrict__ dst, const int* __restrict__ src, int E,
    int sl, int n, int* __restrict__ cnt, int* __restrict__ bkt)
{
    int s  = blockIdx.x & (NSLICE - 1);
    int g  = blockIdx.x >> 3;
    int ng = gridDim.x >> 3;
    int lo = s * sl;
    int hi = lo + sl < n ? lo + sl : n;

    int stride = ng * 256 * 4;
    for (int base = (g * 256 + threadIdx.x) * 4; base < E; base += stride) {
        if (base + 4 <= E) {
            int4v d4 = __builtin_nontemporal_load((const int4v*)(dst + base));
#pragma unroll
            for (int j = 0; j < 4; j++) {
                int d = d4[j];
                if (d >= lo && d < hi) {
                    int sv = __builtin_nontemporal_load(src + base + j);
                    int pos = atomicAdd(&cnt[d], 1);
                    if (pos < CAP) bkt[(size_t)d * CAP + pos] = sv;
                }
            }
        } else {
            for (int e = base; e < E; e++) {
                int d = dst[e];
                if (d >= lo && d < hi) {
                    int pos = atomicAdd(&cnt[d], 1);
                    if (pos < CAP) bkt[(size_t)d * CAP + pos] = src[e];
                }
            }
        }
    }
}

__global__ void dinv_k(const int* __restrict__ cnt, float* __restrict__ dinv, int n) {
    int v = blockIdx.x * blockDim.x + threadIdx.x;
    if (v < n) dinv[v] = rsqrtf((float)(cnt[v] + 1));  // +1 self-loop
}

// ---------------- converters ----------------

__global__ void conv_x_k(const float2* __restrict__ x, const float* __restrict__ dinv,
                         unsigned int* __restrict__ xb, int n) {
    int i = blockIdx.x * blockDim.x + threadIdx.x;   // over n*64 float2s
    if (i < n * 64) {
        float sc = dinv[i >> 6];
        float2 v = x[i];
        xb[i] = pack2(v.x * sc, v.y * sc);
    }
}

__global__ void conv_w_k(const float2* __restrict__ in, unsigned int* __restrict__ out, int n2) {
    int i = blockIdx.x * blockDim.x + threadIdx.x;
    if (i < n2) {
        float2 v = in[i];
        out[i] = pack2(v.x, v.y);
    }
}

// ---------------- gather hop (bf16 rows), one wave per node ----------------
// out[v] = scale_v * ( sum_{s in bkt[v]} in[s] + in[v] ),  scale = SQ ? dinv^2 : dinv
// 8 predicated row-loads in flight per wave (latency/MLP-bound kernel).

template<bool SQ>
__global__ __launch_bounds__(256) void gather_b_k(
    const unsigned int* __restrict__ xin,   // [n][64] bf16-pairs
    const int* __restrict__ cnt, const int* __restrict__ bkt,
    const float* __restrict__ dinv,
    unsigned int* __restrict__ xout, int n)
{
    int v = blockIdx.x * 4 + (threadIdx.x >> 6);
    if (v >= n) return;
    int l = threadIdx.x & 63;
    int c = cnt[v]; if (c > CAP) c = CAP;
    const int* __restrict__ b = bkt + (size_t)v * CAP;

    unsigned int us = xin[(size_t)v * 64 + l];   // self row: issue early
    float ax = 0.f, ay = 0.f;

    for (int i = 0; i < c; i += 8) {
        // bucket row is 256B-aligned, i%8==0 -> in-bounds vector reads of CAP region
        int4v b0 = *(const int4v*)(b + i);
        int4v b1 = *(const int4v*)(b + i + 4);
        int idx[8];
#pragma unroll
        for (int j = 0; j < 4; j++) idx[j]     = (i + j     < c) ? b0[j] : v;  // clamp: poison-safe
#pragma unroll
        for (int j = 0; j < 4; j++) idx[4 + j] = (i + 4 + j < c) ? b1[j] : v;
        unsigned int u[8];
#pragma unroll
        for (int j = 0; j < 8; j++) u[j] = xin[(size_t)idx[j] * 64 + l];
#pragma unroll
        for (int j = 0; j < 8; j++) {
            if (i + j < c) { ax += bf_lo(u[j]); ay += bf_hi(u[j]); }
        }
    }

    ax += bf_lo(us);
    ay += bf_hi(us);

    float dv = dinv[v];
    float sc = SQ ? dv * dv : dv;
    xout[(size_t)v * 64 + l] = pack2(ax * sc, ay * sc);
}

// ---------------- fused MLP + log_softmax via MFMA ----------------
// 256 threads = 4 waves; 64 nodes/block (16 per wave).
__global__ __launch_bounds__(256) void transform_mfma_k(
    const unsigned short* __restrict__ x2b,   // [n][128] bf16
    const unsigned short* __restrict__ w1b,   // [128][128] bf16 (row-major [o][k])
    const float* __restrict__ b1,
    const unsigned short* __restrict__ w2b,   // [64][128] bf16
    const float* __restrict__ b2,
    float* __restrict__ out, int n)
{
    __shared__ __align__(16) unsigned short Hs[64][152];  // 304B row stride

    int t = threadIdx.x;
    int w = t >> 6;        // wave 0..3 -> node rows w*16..w*16+15
    int l = t & 63;
    int lg = l >> 4;       // lane group 0..3
    int ll = l & 15;
    int node0 = blockIdx.x * 64;

    // ---- A frags for GEMM1: X rows (clamped; invalid rows discarded at write) ----
    int nrow = node0 + w * 16 + ll;
    int crow = nrow < n ? nrow : (n - 1);
    const unsigned short* xrow = x2b + (size_t)crow * 128 + lg * 8;
    short8 a[4];
#pragma unroll
    for (int kb = 0; kb < 4; kb++)
        a[kb] = *(const short8*)(xrow + kb * 32);

    // ---- GEMM1: 8 n-tiles x 4 k-blocks ----
    f32x4 acc[8];
#pragma unroll
    for (int nt = 0; nt < 8; nt++) {
        float bv = b1[nt * 16 + ll];
        acc[nt][0] = bv; acc[nt][1] = bv; acc[nt][2] = bv; acc[nt][3] = bv;
    }
#pragma unroll
    for (int nt = 0; nt < 8; nt++) {
        const unsigned short* wrow = w1b + (size_t)(nt * 16 + ll) * 128 + lg * 8;
#pragma unroll
        for (int kb = 0; kb < 4; kb++) {
            short8 bf = *(const short8*)(wrow + kb * 32);
            acc[nt] = __builtin_amdgcn_mfma_f32_16x16x32_bf16(a[kb], bf, acc[nt], 0, 0, 0);
        }
    }

    // ---- relu -> bf16 -> LDS (each wave writes/reads only its own 16-row slice) ----
#pragma unroll
    for (int nt = 0; nt < 8; nt++) {
#pragma unroll
        for (int r = 0; r < 4; r++) {
            float hv = fmaxf(acc[nt][r], 0.f);
            Hs[w * 16 + lg * 4 + r][nt * 16 + ll] = f2bf(hv);
        }
    }
    // intra-wave LDS write->read: lgkmcnt ordering suffices (no barrier needed)

    // ---- A frags for GEMM2 from Hs ----
    short8 ha[4];
#pragma unroll
    for (int kb = 0; kb < 4; kb++)
        ha[kb] = *(const short8*)&Hs[w * 16 + ll][kb * 32 + lg * 8];

    // ---- GEMM2: 4 n-tiles x 4 k-blocks ----
    f32x4 acc2[4];
#pragma unroll
    for (int nt = 0; nt < 4; nt++) {
        float bv = b2[nt * 16 + ll];
        acc2[nt][0] = bv; acc2[nt][1] = bv; acc2[nt][2] = bv; acc2[nt][3] = bv;
        const unsigned short* wrow = w2b + (size_t)(nt * 16 + ll) * 128 + lg * 8;
#pragma unroll
        for (int kb = 0; kb < 4; kb++) {
            short8 bf = *(const short8*)(wrow + kb * 32);
            acc2[nt] = __builtin_amdgcn_mfma_f32_16x16x32_bf16(ha[kb], bf, acc2[nt], 0, 0, 0);
        }
    }

    // ---- log_softmax per node row; lane holds rows (lg*4+r), cols nt*16+ll ----
#pragma unroll
    for (int r = 0; r < 4; r++) {
        float m = fmaxf(fmaxf(acc2[0][r], acc2[1][r]), fmaxf(acc2[2][r], acc2[3][r]));
        m = fmaxf(m, __shfl_xor(m, 1));
        m = fmaxf(m, __shfl_xor(m, 2));
        m = fmaxf(m, __shfl_xor(m, 4));
        m = fmaxf(m, __shfl_xor(m, 8));
        float s = __expf(acc2[0][r] - m) + __expf(acc2[1][r] - m) +
                  __expf(acc2[2][r] - m) + __expf(acc2[3][r] - m);
        s += __shfl_xor(s, 1);
        s += __shfl_xor(s, 2);
        s += __shfl_xor(s, 4);
        s += __shfl_xor(s, 8);
        float lse = m + __logf(s);
        int node = node0 + w * 16 + lg * 4 + r;
        if (node < n) {
#pragma unroll
            for (int nt = 0; nt < 4; nt++)
                out[(size_t)node * 64 + nt * 16 + ll] = acc2[nt][r] - lse;
        }
    }
}

// ---------------- launch ----------------

static inline size_t align256(size_t x) { return (x + 255) & ~(size_t)255; }

extern "C" void kernel_launch(void* const* d_in, const int* in_sizes, int n_in,
                              void* d_out, int out_size, void* d_ws, size_t ws_size,
                              hipStream_t stream) {
    const float* x  = (const float*)d_in[0];
    const int*   ei = (const int*)d_in[1];
    const float* W1 = (const float*)d_in[2];
    const float* b1 = (const float*)d_in[3];
    const float* W2 = (const float*)d_in[4];
    const float* b2 = (const float*)d_in[5];
    float* out = (float*)d_out;

    int n = in_sizes[0] / 128;        // 100000
    int E = in_sizes[1] / 2;          // 1600000
    const int* src = ei;
    const int* dst = ei + E;

    // workspace layout
    char* w = (char*)d_ws;
    size_t off = 0;
    int*          cnt  = (int*)(w + off);          off += align256((size_t)n * sizeof(int));
    float*        dinv = (float*)(w + off);        off += align256((size_t)n * sizeof(float));
    int*          bkt  = (int*)(w + off);          off += align256((size_t)n * CAP * sizeof(int));
    unsigned int* xb   = (unsigned int*)(w + off); off += align256((size_t)n * 64 * sizeof(unsigned int));
    unsigned int* z1b  = (unsigned int*)(w + off); off += align256((size_t)n * 64 * sizeof(unsigned int));
    unsigned int* x2b  = (unsigned int*)(w + off); off += align256((size_t)n * 64 * sizeof(unsigned int));
    unsigned int* w1b  = (unsigned int*)(w + off); off += align256((size_t)128 * 64 * sizeof(unsigned int));
    unsigned int* w2b  = (unsigned int*)(w + off);

    int tb = 256;
    int gb_n = (n + tb - 1) / tb;
    int gb_x = (n * 64 + tb - 1) / tb;
    int gb_g = (n + 3) / 4;

    // degrees + buckets: one launch, slice = blockIdx%8 (one XCD owns each slice)
    (void)hipMemsetAsync(cnt, 0, (size_t)n * sizeof(int), stream);
    int sl = (n + NSLICE - 1) / NSLICE;       // 12500
    fill_swz_k<<<2048, tb, 0, stream>>>(dst, src, E, sl, n, cnt, bkt);
    dinv_k<<<gb_n, tb, 0, stream>>>(cnt, dinv, n);

    // converters
    conv_x_k<<<gb_x, tb, 0, stream>>>((const float2*)x, dinv, xb, n);
    conv_w_k<<<(128 * 64 + tb - 1) / tb, tb, 0, stream>>>((const float2*)W1, w1b, 128 * 64);
    conv_w_k<<<(64 * 64 + tb - 1) / tb, tb, 0, stream>>>((const float2*)W2, w2b, 64 * 64);

    // hop 1: xb -> z1b (scale dinv^2), hop 2: z1b -> x2b (scale dinv)
    gather_b_k<true ><<<gb_g, tb, 0, stream>>>(xb,  cnt, bkt, dinv, z1b, n);
    gather_b_k<false><<<gb_g, tb, 0, stream>>>(z1b, cnt, bkt, dinv, x2b, n);

    // fused MFMA MLP + log_softmax
    transform_mfma_k<<<(n + 63) / 64, 256, 0, stream>>>(
        (const unsigned short*)x2b, (const unsigned short*)w1b, b1,
        (const unsigned short*)w2b, b2, out, n);
}